// Round 4
// baseline (311.891 us; speedup 1.0000x reference)
//
#include <hip/hip_runtime.h>
#include <math.h>

#define DIM   1024
#define HEADS 16
#define DH    64
#define ROT   128
#define BATCH 2
#define SEQ   2048
#define ROWS  (BATCH*SEQ)        // 4096
#define PCOLS (DIM + 2*DH)       // 1152 = [q(1024) | k(64) | v(64)] per side
#define ASCALE 0.08838834764831845f   // 1/sqrt(128), folded into qbuf

typedef short bf16x8 __attribute__((ext_vector_type(8)));
typedef float f32x16 __attribute__((ext_vector_type(16)));

static __device__ __forceinline__ unsigned short f2bf(float f) {
    union { float f; unsigned u; } v; v.f = f;
    unsigned r = v.u + 0x7fffu + ((v.u >> 16) & 1u);   // RNE (no NaN inputs here)
    return (unsigned short)(r >> 16);
}
static __device__ __forceinline__ float bf2f(unsigned short u) {
    union { unsigned u; float f; } v; v.u = (unsigned)u << 16;
    return v.f;
}

#define GL2LDS(gp, lp) __builtin_amdgcn_global_load_lds(                    \
    (const __attribute__((address_space(1))) void*)(gp),                    \
    (__attribute__((address_space(3))) void*)(lp), 16, 0, 0)

// ---------------------------------------------------------------------------
// Convert fp32 inputs -> bf16 staging buffers + rotary cos/sin table.
// xbf[2][4096][1024], wbf[2][1152][1024], tbl[2048][64] of float2 {cos,sin}
// ---------------------------------------------------------------------------
__global__ __launch_bounds__(256) void convert_kernel(
    const float* __restrict__ x, const float* __restrict__ a,
    const float* __restrict__ Wq_x, const float* __restrict__ Wkv_x,
    const float* __restrict__ Wq_a, const float* __restrict__ Wkv_a,
    unsigned short* __restrict__ xbf, unsigned short* __restrict__ wbf,
    float2* __restrict__ tbl)
{
    const int blk = blockIdx.x;
    const float LN1E4_64 = 0.14391156831213f;   // ln(10000)/64
    if (blk >= 2624) {                           // rotary table segment
        int local = blk - 2624;                  // 0..127
        int pos = local * 16 + (threadIdx.x >> 4);
        int i   = threadIdx.x & 15;
        #pragma unroll
        for (int j = 0; j < 4; j++) {
            int jd = i * 4 + j;
            float th = (float)pos * expf(-LN1E4_64 * (float)jd);
            float sn, cs; sincosf(th, &sn, &cs);
            tbl[pos * 64 + jd] = make_float2(cs, sn);
        }
        return;
    }
    const float* s; unsigned short* d; int seg0;
    if      (blk < 1024) { s = x;     d = xbf;           seg0 = 0;    }
    else if (blk < 2048) { s = a;     d = xbf + 4194304; seg0 = 1024; }
    else if (blk < 2304) { s = Wq_x;  d = wbf;           seg0 = 2048; }
    else if (blk < 2336) { s = Wkv_x; d = wbf + 1048576; seg0 = 2304; }
    else if (blk < 2592) { s = Wq_a;  d = wbf + 1179648; seg0 = 2336; }
    else                 { s = Wkv_a; d = wbf + 2228224; seg0 = 2592; }
    long lb = ((long)blk - seg0) * 1024;
    #pragma unroll
    for (int j = 0; j < 4; j++) {
        long idx = lb + j * 256 + threadIdx.x;
        float4 v = ((const float4*)s)[idx];
        ((ushort4*)d)[idx] = make_ushort4(f2bf(v.x), f2bf(v.y), f2bf(v.z), f2bf(v.w));
    }
}

// ---------------------------------------------------------------------------
// MFMA GEMM (bf16, 32x32x16) — unchanged from R2.
// ---------------------------------------------------------------------------
__global__ __launch_bounds__(256) void mfma_gemm_kernel(
    const unsigned short* __restrict__ xbf, const unsigned short* __restrict__ wbf,
    unsigned short* __restrict__ Pbf)
{
    const int mt = blockIdx.x, jt = blockIdx.y, side = blockIdx.z;
    const unsigned short* Ag = xbf + ((size_t)side * ROWS  + mt * 128) * DIM;
    const unsigned short* Bg = wbf + ((size_t)side * PCOLS + jt * 128) * DIM;
    unsigned short* Pp = Pbf + (size_t)side * ROWS * PCOLS;

    __shared__ __align__(16) unsigned short As[128 * 32];
    __shared__ __align__(16) unsigned short Bs[128 * 32];

    const int tid  = threadIdx.x;
    const int wave = tid >> 6, lane = tid & 63;
    const int m = lane & 31, hl = lane >> 5;
    const int wr = wave >> 1, wc = wave & 1;

    f32x16 acc[2][2];
    #pragma unroll
    for (int i2 = 0; i2 < 2; i2++)
        #pragma unroll
        for (int j2 = 0; j2 < 2; j2++) acc[i2][j2] = 0.0f;

    int sr[2], sg[2]; unsigned ldsb[2];
    #pragma unroll
    for (int it = 0; it < 2; it++) {
        int s = it * 256 + tid;
        sr[it] = s >> 2;
        sg[it] = (s & 3) ^ ((sr[it] >> 1) & 3);
        ldsb[it] = (unsigned)(it * 256 + wave * 64) * 16;
    }

    for (int k0 = 0; k0 < DIM; k0 += 32) {
        __syncthreads();
        #pragma unroll
        for (int it = 0; it < 2; it++) {
            GL2LDS(Ag + (size_t)sr[it] * DIM + k0 + sg[it] * 8, (char*)As + ldsb[it]);
            GL2LDS(Bg + (size_t)sr[it] * DIM + k0 + sg[it] * 8, (char*)Bs + ldsb[it]);
        }
        __syncthreads();
        #pragma unroll
        for (int kp = 0; kp < 2; kp++) {
            bf16x8 af[2], bff[2];
            #pragma unroll
            for (int t2 = 0; t2 < 2; t2++) {
                int ra = wr * 64 + t2 * 32 + m;
                int ga = (kp * 2 + hl) ^ ((ra >> 1) & 3);
                af[t2] = *(const bf16x8*)&As[ra * 32 + ga * 8];
                int rb = wc * 64 + t2 * 32 + m;
                int gb = (kp * 2 + hl) ^ ((rb >> 1) & 3);
                bff[t2] = *(const bf16x8*)&Bs[rb * 32 + gb * 8];
            }
            #pragma unroll
            for (int i2 = 0; i2 < 2; i2++)
                #pragma unroll
                for (int j2 = 0; j2 < 2; j2++)
                    acc[i2][j2] = __builtin_amdgcn_mfma_f32_32x32x16_bf16(
                        af[i2], bff[j2], acc[i2][j2], 0, 0, 0);
        }
    }

    const int m0 = mt * 128 + wr * 64;
    const int n0 = jt * 128 + wc * 64;
    #pragma unroll
    for (int i2 = 0; i2 < 2; i2++)
        #pragma unroll
        for (int j2 = 0; j2 < 2; j2++)
            #pragma unroll
            for (int r = 0; r < 16; r++) {
                int row = m0 + i2 * 32 + (r & 3) + 8 * (r >> 2) + 4 * hl;
                int col = n0 + j2 * 32 + m;
                Pp[(size_t)row * PCOLS + col] = f2bf(acc[i2][j2][r]);
            }
}

// ---------------------------------------------------------------------------
// Fuse: l2norm + scale + concat + rotary (bf16 P in, table-driven rotary).
// ---------------------------------------------------------------------------
__global__ __launch_bounds__(256) void fuse_kernel(
    const unsigned short* __restrict__ Pbf,
    const float* __restrict__ qx_scale, const float* __restrict__ qa_scale,
    const float* __restrict__ kx_scale, const float* __restrict__ ka_scale,
    const float2* __restrict__ tbl,
    unsigned short* __restrict__ qbuf, unsigned short* __restrict__ kbuf,
    unsigned short* __restrict__ vbufT)
{
    const int row = blockIdx.x;            // b*SEQ + pos
    const int b = row >> 11, pos = row & 2047;
    const unsigned short* Px = Pbf + (size_t)row * PCOLS;
    const unsigned short* Pa = Pbf + (size_t)ROWS * PCOLS + (size_t)row * PCOLS;
    const int tid = threadIdx.x;
    const int h = tid >> 4, i = tid & 15;
    const float2* tb = tbl + pos * 64;

    // ---- Q ----
    ushort4 xu = *(const ushort4*)(Px + h * DH + i * 4);
    ushort4 au = *(const ushort4*)(Pa + h * DH + i * 4);
    float xr[4] = {bf2f(xu.x), bf2f(xu.y), bf2f(xu.z), bf2f(xu.w)};
    float ar[4] = {bf2f(au.x), bf2f(au.y), bf2f(au.z), bf2f(au.w)};
    float ssx = xr[0]*xr[0] + xr[1]*xr[1] + xr[2]*xr[2] + xr[3]*xr[3];
    float ssa = ar[0]*ar[0] + ar[1]*ar[1] + ar[2]*ar[2] + ar[3]*ar[3];
    #pragma unroll
    for (int off = 1; off < 16; off <<= 1) {
        ssx += __shfl_xor(ssx, off, 16);
        ssa += __shfl_xor(ssa, off, 16);
    }
    float inx = 1.0f / fmaxf(sqrtf(ssx), 1e-12f);
    float ina = 1.0f / fmaxf(sqrtf(ssa), 1e-12f);
    unsigned short qlo[4], qhi[4];
    #pragma unroll
    for (int j = 0; j < 4; j++) {
        int jd = i * 4 + j;
        float qx = xr[j] * inx * qx_scale[h * DH + jd];
        float qa = ar[j] * ina * qa_scale[h * DH + jd];
        float2 cssn = tb[jd];
        qlo[j] = f2bf((qx * cssn.x - qa * cssn.y) * ASCALE);
        qhi[j] = f2bf((qa * cssn.x + qx * cssn.y) * ASCALE);
    }
    unsigned short* qp = qbuf + (((size_t)(b * HEADS + h)) * SEQ + pos) * ROT;
    *(ushort4*)(qp + i * 4)      = make_ushort4(qlo[0], qlo[1], qlo[2], qlo[3]);
    *(ushort4*)(qp + DH + i * 4) = make_ushort4(qhi[0], qhi[1], qhi[2], qhi[3]);

    // ---- K ----
    if (tid < 16) {
        ushort4 kxu = *(const ushort4*)(Px + DIM + tid * 4);
        ushort4 kau = *(const ushort4*)(Pa + DIM + tid * 4);
        float kxr[4] = {bf2f(kxu.x), bf2f(kxu.y), bf2f(kxu.z), bf2f(kxu.w)};
        float kar[4] = {bf2f(kau.x), bf2f(kau.y), bf2f(kau.z), bf2f(kau.w)};
        float sx = kxr[0]*kxr[0] + kxr[1]*kxr[1] + kxr[2]*kxr[2] + kxr[3]*kxr[3];
        float sa = kar[0]*kar[0] + kar[1]*kar[1] + kar[2]*kar[2] + kar[3]*kar[3];
        #pragma unroll
        for (int off = 1; off < 16; off <<= 1) {
            sx += __shfl_xor(sx, off, 16);
            sa += __shfl_xor(sa, off, 16);
        }
        float ikx = 1.0f / fmaxf(sqrtf(sx), 1e-12f);
        float ika = 1.0f / fmaxf(sqrtf(sa), 1e-12f);
        unsigned short klo[4], khi[4];
        #pragma unroll
        for (int j = 0; j < 4; j++) {
            int jd = tid * 4 + j;
            float kx = kxr[j] * ikx * kx_scale[jd];
            float ka = kar[j] * ika * ka_scale[jd];
            float2 cssn = tb[jd];
            klo[j] = f2bf(kx * cssn.x - ka * cssn.y);
            khi[j] = f2bf(ka * cssn.x + kx * cssn.y);
        }
        unsigned short* kp = kbuf + ((size_t)b * SEQ + pos) * ROT;
        *(ushort4*)(kp + tid * 4)      = make_ushort4(klo[0], klo[1], klo[2], klo[3]);
        *(ushort4*)(kp + DH + tid * 4) = make_ushort4(khi[0], khi[1], khi[2], khi[3]);
    }
    // ---- V (transposed store, exact bf16 copy) ----
    if (tid >= 64 && tid < 96) {
        int iv = tid - 64;
        unsigned short* vT = vbufT + (size_t)b * ROT * SEQ + pos;
        const unsigned short* src; int d;
        if (iv < 16) { src = Px + DIM + DH + iv * 4;        d = iv * 4;              }
        else         { src = Pa + DIM + DH + (iv - 16) * 4; d = DH + (iv - 16) * 4;  }
        ushort4 v4 = *(const ushort4*)src;
        vT[(size_t)(d + 0) * SEQ] = v4.x;
        vT[(size_t)(d + 1) * SEQ] = v4.y;
        vT[(size_t)(d + 2) * SEQ] = v4.z;
        vT[(size_t)(d + 3) * SEQ] = v4.w;
    }
}

// ---------------------------------------------------------------------------
// MFMA flash attention, key-split:
//   block = 4 waves = 2 q-tiles (qt) x 2 key-halves (ks); 64 q-rows/block.
//   grid (32,16,2) = 1024 blocks -> 4 blocks/CU, 16 waves/CU (2x R2).
//   Each wave: 32q x 1024 keys in 32-key tiles; K via global_load_lds
//   (swizzled source), V manual store w/ (d>>1)&3 granule swizzle.
//   ks-pairs combine unnormalized oacc+lsum via LDS at the end (valid since
//   softmax has no max-tracking: partial sums add exactly).
// ---------------------------------------------------------------------------
__global__ __launch_bounds__(256, 4) void attn_kernel(
    const unsigned short* __restrict__ qbuf,
    const unsigned short* __restrict__ kbuf,
    const unsigned short* __restrict__ vbufT,
    float* __restrict__ out)
{
    const int qb = blockIdx.x, h = blockIdx.y, b = blockIdx.z;
    // staging: Ks[2 sets][32*128] + Vs[2 sets][128*32] = 32 KB
    // combine: 2 qt * 64 lanes * 65 floats = 33280 B  -> max 33280
    __shared__ __align__(16) char smem[33280];
    const int tid  = threadIdx.x;
    const int wave = tid >> 6, lane = tid & 63;
    const int qt = wave & 1, ks = wave >> 1;
    const int m = lane & 31, hl = lane >> 5;
    const int q0 = qb * 64 + qt * 32;

    unsigned short* KsAll = (unsigned short*)smem;              // [set][32*128]
    unsigned short* VsAll = (unsigned short*)(smem + 16384);    // [set][128*32]
    unsigned short* Ks = KsAll + ks * 4096;
    unsigned short* Vs = VsAll + ks * 4096;

    // Q resident (B-frag): chunk c covers d = c*16 + hl*8 + j
    bf16x8 qf[8];
    {
        const unsigned short* qp = qbuf + (((size_t)(b * HEADS + h)) * SEQ + q0 + m) * ROT + hl * 8;
        #pragma unroll
        for (int c = 0; c < 8; c++) qf[c] = *(const bf16x8*)(qp + c * 16);
    }

    f32x16 oacc[4];
    #pragma unroll
    for (int dt = 0; dt < 4; dt++) oacc[dt] = 0.0f;
    float lsum = 0.f;

    const unsigned short* kb_ = kbuf  + (size_t)b * SEQ * ROT;
    const unsigned short* vb_ = vbufT + (size_t)b * ROT * SEQ;

    for (int t = 0; t < 32; t++) {
        __syncthreads();
        // ---- stage both tile-sets with all 256 threads ----
        #pragma unroll
        for (int it = 0; it < 4; it++) {
            // K: 1024 granules over 2 sets; set s>>9, row (s>>4)&31, g s&15
            int s = it * 256 + tid;
            int set = s >> 9, krow = (s >> 4) & 31, kg = s & 15;
            int kgg = kg ^ (krow & 15);
            int kt = set * 1024 + t * 32;
            GL2LDS(kb_ + (size_t)(kt + krow) * ROT + kgg * 8,
                   (char*)KsAll + (unsigned)(it * 256 + wave * 64) * 16);
            // V: set sv>>9, d (sv>>2)&127, g sv&3; swizzle g^((d>>1)&3)
            int d = (s >> 2) & 127, vg = s & 3;
            int vgg = vg ^ ((d >> 1) & 3);
            uint4 vv = *(const uint4*)(vb_ + (size_t)d * SEQ + kt + vgg * 8);
            *(uint4*)&VsAll[(size_t)s * 8] = vv;
        }
        __syncthreads();

        // ---- S^T = K tile @ Q^T (32 keys x 32 qrows) ----
        f32x16 st = 0.0f;
        #pragma unroll
        for (int c = 0; c < 8; c++) {
            bf16x8 af = *(const bf16x8*)&Ks[m * 128 + (((2 * c + hl) ^ (m & 15)) << 3)];
            st = __builtin_amdgcn_mfma_f32_32x32x16_bf16(af, qf[c], st, 0, 0, 0);
        }
        float p[16];
        #pragma unroll
        for (int r = 0; r < 16; r++) { p[r] = __expf(st[r]); lsum += p[r]; }

        // ---- PV over two 16-key windows ----
        #pragma unroll
        for (int w = 0; w < 2; w++) {
            float pj[8];
            #pragma unroll
            for (int tq = 0; tq < 4; tq++) {
                float send = hl ? p[8 * w + tq]     : p[8 * w + 4 + tq];
                float own  = hl ? p[8 * w + 4 + tq] : p[8 * w + tq];
                float recv = __shfl_xor(send, 32);
                pj[tq]     = hl ? recv : own;
                pj[4 + tq] = hl ? own  : recv;
            }
            bf16x8 aP;
            #pragma unroll
            for (int j = 0; j < 8; j++) aP[j] = (short)f2bf(pj[j]);
            #pragma unroll
            for (int dt = 0; dt < 4; dt++) {
                int d = dt * 32 + m;
                bf16x8 vf = *(const bf16x8*)&Vs[d * 32 + (((2 * w + hl) ^ ((d >> 1) & 3)) << 3)];
                oacc[dt] = __builtin_amdgcn_mfma_f32_32x32x16_bf16(aP, vf, oacc[dt], 0, 0, 0);
            }
        }
    }

    // ---- combine ks halves through LDS ----
    __syncthreads();
    float* cb = (float*)smem;
    if (ks == 1) {
        float* dst = cb + (size_t)(qt * 64 + lane) * 65;
        #pragma unroll
        for (int dt = 0; dt < 4; dt++)
            #pragma unroll
            for (int r = 0; r < 16; r++) dst[dt * 16 + r] = oacc[dt][r];
        dst[64] = lsum;
    }
    __syncthreads();
    if (ks == 0) {
        const float* src = cb + (size_t)(qt * 64 + lane) * 65;
        #pragma unroll
        for (int dt = 0; dt < 4; dt++)
            #pragma unroll
            for (int r = 0; r < 16; r++) oacc[dt][r] += src[dt * 16 + r];
        lsum += src[64];
        lsum += __shfl_xor(lsum, 32);    // other half-lane's keys

        float* ob = out + ((size_t)(b * SEQ + q0)) * (HEADS * ROT) + h * ROT + m;
        #pragma unroll
        for (int r = 0; r < 16; r++) {
            int qrow = (r & 3) + 8 * (r >> 2) + 4 * hl;
            float linv = 1.0f / __shfl(lsum, qrow);
            float* orow = ob + (size_t)qrow * (HEADS * ROT);
            #pragma unroll
            for (int dt = 0; dt < 4; dt++) orow[dt * 32] = oacc[dt][r] * linv;
        }
    }
}

// ---------------------------------------------------------------------------
extern "C" void kernel_launch(void* const* d_in, const int* in_sizes, int n_in,
                              void* d_out, int out_size, void* d_ws, size_t ws_size,
                              hipStream_t stream) {
    (void)in_sizes; (void)n_in; (void)out_size; (void)ws_size;
    const float* x        = (const float*)d_in[0];
    const float* a        = (const float*)d_in[1];
    const float* Wq_x     = (const float*)d_in[2];
    const float* Wkv_x    = (const float*)d_in[3];
    const float* Wq_a     = (const float*)d_in[4];
    const float* Wkv_a    = (const float*)d_in[5];
    const float* qx_scale = (const float*)d_in[6];
    const float* qa_scale = (const float*)d_in[7];
    const float* kx_scale = (const float*)d_in[8];
    const float* ka_scale = (const float*)d_in[9];
    float* out = (float*)d_out;

    // ws layout (shorts): Pbf 9.44M | qbuf 8.39M | kbuf .52M | vbufT .52M
    //                     | xbf 8.39M | wbf 2.36M | tbl (1MB float2) => 60.3MB
    unsigned short* Pbf   = (unsigned short*)d_ws;
    unsigned short* qbuf  = Pbf   + (size_t)2 * ROWS * PCOLS;
    unsigned short* kbuf  = qbuf  + (size_t)BATCH * HEADS * SEQ * ROT;
    unsigned short* vbufT = kbuf  + (size_t)BATCH * SEQ * ROT;
    unsigned short* xbf   = vbufT + (size_t)BATCH * SEQ * ROT;
    unsigned short* wbf   = xbf   + (size_t)2 * ROWS * DIM;
    float2*         tbl   = (float2*)(wbf + (size_t)2 * PCOLS * DIM);

    convert_kernel<<<dim3(2752), 256, 0, stream>>>(x, a, Wq_x, Wkv_x, Wq_a, Wkv_a,
                                                   xbf, wbf, tbl);
    mfma_gemm_kernel<<<dim3(32, 9, 2), 256, 0, stream>>>(xbf, wbf, Pbf);
    fuse_kernel<<<dim3(ROWS), 256, 0, stream>>>(Pbf, qx_scale, qa_scale, kx_scale, ka_scale,
                                                tbl, qbuf, kbuf, vbufT);
    attn_kernel<<<dim3(SEQ / 64, HEADS, BATCH), 256, 0, stream>>>(qbuf, kbuf, vbufT, out);
}

// Round 5
// 232.647 us; speedup vs baseline: 1.3406x; 1.3406x over previous
//
#include <hip/hip_runtime.h>
#include <math.h>

#define DIM   1024
#define HEADS 16
#define DH    64
#define ROT   128
#define BATCH 2
#define SEQ   2048
#define ROWS  (BATCH*SEQ)        // 4096
#define PCOLS (DIM + 2*DH)       // 1152 = [q(1024) | k(64) | v(64)] per side
#define ASCALE 0.08838834764831845f   // 1/sqrt(128), folded into qbuf

typedef short bf16x8 __attribute__((ext_vector_type(8)));
typedef float f32x16 __attribute__((ext_vector_type(16)));

static __device__ __forceinline__ unsigned short f2bf(float f) {
    union { float f; unsigned u; } v; v.f = f;
    unsigned r = v.u + 0x7fffu + ((v.u >> 16) & 1u);   // RNE (no NaN inputs here)
    return (unsigned short)(r >> 16);
}
static __device__ __forceinline__ float bf2f(unsigned short u) {
    union { unsigned u; float f; } v; v.u = (unsigned)u << 16;
    return v.f;
}

#define GL2LDS(gp, lp) __builtin_amdgcn_global_load_lds(                    \
    (const __attribute__((address_space(1))) void*)(gp),                    \
    (__attribute__((address_space(3))) void*)(lp), 16, 0, 0)
#define CFENCE() asm volatile("" ::: "memory")
// s_waitcnt imm: vmcnt[3:0]|[15:14], expcnt[6:4], lgkmcnt[11:8]; others maxed
#define WAIT_VM8()  __builtin_amdgcn_s_waitcnt(0xF78)   // vmcnt(8)
#define WAIT_VM0()  __builtin_amdgcn_s_waitcnt(0xF70)   // vmcnt(0)

// ---------------------------------------------------------------------------
// Convert fp32 inputs -> bf16 staging buffers + rotary cos/sin table.
// ---------------------------------------------------------------------------
__global__ __launch_bounds__(256) void convert_kernel(
    const float* __restrict__ x, const float* __restrict__ a,
    const float* __restrict__ Wq_x, const float* __restrict__ Wkv_x,
    const float* __restrict__ Wq_a, const float* __restrict__ Wkv_a,
    unsigned short* __restrict__ xbf, unsigned short* __restrict__ wbf,
    float2* __restrict__ tbl)
{
    const int blk = blockIdx.x;
    const float LN1E4_64 = 0.14391156831213f;   // ln(10000)/64
    if (blk >= 2624) {                           // rotary table segment
        int local = blk - 2624;                  // 0..127
        int pos = local * 16 + (threadIdx.x >> 4);
        int i   = threadIdx.x & 15;
        #pragma unroll
        for (int j = 0; j < 4; j++) {
            int jd = i * 4 + j;
            float th = (float)pos * expf(-LN1E4_64 * (float)jd);
            float sn, cs; sincosf(th, &sn, &cs);
            tbl[pos * 64 + jd] = make_float2(cs, sn);
        }
        return;
    }
    const float* s; unsigned short* d; int seg0;
    if      (blk < 1024) { s = x;     d = xbf;           seg0 = 0;    }
    else if (blk < 2048) { s = a;     d = xbf + 4194304; seg0 = 1024; }
    else if (blk < 2304) { s = Wq_x;  d = wbf;           seg0 = 2048; }
    else if (blk < 2336) { s = Wkv_x; d = wbf + 1048576; seg0 = 2304; }
    else if (blk < 2592) { s = Wq_a;  d = wbf + 1179648; seg0 = 2336; }
    else                 { s = Wkv_a; d = wbf + 2228224; seg0 = 2592; }
    long lb = ((long)blk - seg0) * 1024;
    #pragma unroll
    for (int j = 0; j < 4; j++) {
        long idx = lb + j * 256 + threadIdx.x;
        float4 v = ((const float4*)s)[idx];
        ((ushort4*)d)[idx] = make_ushort4(f2bf(v.x), f2bf(v.y), f2bf(v.z), f2bf(v.w));
    }
}

// ---------------------------------------------------------------------------
// MFMA GEMM (bf16, 32x32x16) — unchanged from R2.
// ---------------------------------------------------------------------------
__global__ __launch_bounds__(256) void mfma_gemm_kernel(
    const unsigned short* __restrict__ xbf, const unsigned short* __restrict__ wbf,
    unsigned short* __restrict__ Pbf)
{
    const int mt = blockIdx.x, jt = blockIdx.y, side = blockIdx.z;
    const unsigned short* Ag = xbf + ((size_t)side * ROWS  + mt * 128) * DIM;
    const unsigned short* Bg = wbf + ((size_t)side * PCOLS + jt * 128) * DIM;
    unsigned short* Pp = Pbf + (size_t)side * ROWS * PCOLS;

    __shared__ __align__(16) unsigned short As[128 * 32];
    __shared__ __align__(16) unsigned short Bs[128 * 32];

    const int tid  = threadIdx.x;
    const int wave = tid >> 6, lane = tid & 63;
    const int m = lane & 31, hl = lane >> 5;
    const int wr = wave >> 1, wc = wave & 1;

    f32x16 acc[2][2];
    #pragma unroll
    for (int i2 = 0; i2 < 2; i2++)
        #pragma unroll
        for (int j2 = 0; j2 < 2; j2++) acc[i2][j2] = 0.0f;

    int sr[2], sg[2]; unsigned ldsb[2];
    #pragma unroll
    for (int it = 0; it < 2; it++) {
        int s = it * 256 + tid;
        sr[it] = s >> 2;
        sg[it] = (s & 3) ^ ((sr[it] >> 1) & 3);
        ldsb[it] = (unsigned)(it * 256 + wave * 64) * 16;
    }

    for (int k0 = 0; k0 < DIM; k0 += 32) {
        __syncthreads();
        #pragma unroll
        for (int it = 0; it < 2; it++) {
            GL2LDS(Ag + (size_t)sr[it] * DIM + k0 + sg[it] * 8, (char*)As + ldsb[it]);
            GL2LDS(Bg + (size_t)sr[it] * DIM + k0 + sg[it] * 8, (char*)Bs + ldsb[it]);
        }
        __syncthreads();
        #pragma unroll
        for (int kp = 0; kp < 2; kp++) {
            bf16x8 af[2], bff[2];
            #pragma unroll
            for (int t2 = 0; t2 < 2; t2++) {
                int ra = wr * 64 + t2 * 32 + m;
                int ga = (kp * 2 + hl) ^ ((ra >> 1) & 3);
                af[t2] = *(const bf16x8*)&As[ra * 32 + ga * 8];
                int rb = wc * 64 + t2 * 32 + m;
                int gb = (kp * 2 + hl) ^ ((rb >> 1) & 3);
                bff[t2] = *(const bf16x8*)&Bs[rb * 32 + gb * 8];
            }
            #pragma unroll
            for (int i2 = 0; i2 < 2; i2++)
                #pragma unroll
                for (int j2 = 0; j2 < 2; j2++)
                    acc[i2][j2] = __builtin_amdgcn_mfma_f32_32x32x16_bf16(
                        af[i2], bff[j2], acc[i2][j2], 0, 0, 0);
        }
    }

    const int m0 = mt * 128 + wr * 64;
    const int n0 = jt * 128 + wc * 64;
    #pragma unroll
    for (int i2 = 0; i2 < 2; i2++)
        #pragma unroll
        for (int j2 = 0; j2 < 2; j2++)
            #pragma unroll
            for (int r = 0; r < 16; r++) {
                int row = m0 + i2 * 32 + (r & 3) + 8 * (r >> 2) + 4 * hl;
                int col = n0 + j2 * 32 + m;
                Pp[(size_t)row * PCOLS + col] = f2bf(acc[i2][j2][r]);
            }
}

// ---------------------------------------------------------------------------
// Fuse: l2norm + scale + concat + rotary (bf16 P in, table-driven rotary).
// ---------------------------------------------------------------------------
__global__ __launch_bounds__(256) void fuse_kernel(
    const unsigned short* __restrict__ Pbf,
    const float* __restrict__ qx_scale, const float* __restrict__ qa_scale,
    const float* __restrict__ kx_scale, const float* __restrict__ ka_scale,
    const float2* __restrict__ tbl,
    unsigned short* __restrict__ qbuf, unsigned short* __restrict__ kbuf,
    unsigned short* __restrict__ vbufT)
{
    const int row = blockIdx.x;            // b*SEQ + pos
    const int b = row >> 11, pos = row & 2047;
    const unsigned short* Px = Pbf + (size_t)row * PCOLS;
    const unsigned short* Pa = Pbf + (size_t)ROWS * PCOLS + (size_t)row * PCOLS;
    const int tid = threadIdx.x;
    const int h = tid >> 4, i = tid & 15;
    const float2* tb = tbl + pos * 64;

    // ---- Q ----
    ushort4 xu = *(const ushort4*)(Px + h * DH + i * 4);
    ushort4 au = *(const ushort4*)(Pa + h * DH + i * 4);
    float xr[4] = {bf2f(xu.x), bf2f(xu.y), bf2f(xu.z), bf2f(xu.w)};
    float ar[4] = {bf2f(au.x), bf2f(au.y), bf2f(au.z), bf2f(au.w)};
    float ssx = xr[0]*xr[0] + xr[1]*xr[1] + xr[2]*xr[2] + xr[3]*xr[3];
    float ssa = ar[0]*ar[0] + ar[1]*ar[1] + ar[2]*ar[2] + ar[3]*ar[3];
    #pragma unroll
    for (int off = 1; off < 16; off <<= 1) {
        ssx += __shfl_xor(ssx, off, 16);
        ssa += __shfl_xor(ssa, off, 16);
    }
    float inx = 1.0f / fmaxf(sqrtf(ssx), 1e-12f);
    float ina = 1.0f / fmaxf(sqrtf(ssa), 1e-12f);
    unsigned short qlo[4], qhi[4];
    #pragma unroll
    for (int j = 0; j < 4; j++) {
        int jd = i * 4 + j;
        float qx = xr[j] * inx * qx_scale[h * DH + jd];
        float qa = ar[j] * ina * qa_scale[h * DH + jd];
        float2 cssn = tb[jd];
        qlo[j] = f2bf((qx * cssn.x - qa * cssn.y) * ASCALE);
        qhi[j] = f2bf((qa * cssn.x + qx * cssn.y) * ASCALE);
    }
    unsigned short* qp = qbuf + (((size_t)(b * HEADS + h)) * SEQ + pos) * ROT;
    *(ushort4*)(qp + i * 4)      = make_ushort4(qlo[0], qlo[1], qlo[2], qlo[3]);
    *(ushort4*)(qp + DH + i * 4) = make_ushort4(qhi[0], qhi[1], qhi[2], qhi[3]);

    // ---- K ----
    if (tid < 16) {
        ushort4 kxu = *(const ushort4*)(Px + DIM + tid * 4);
        ushort4 kau = *(const ushort4*)(Pa + DIM + tid * 4);
        float kxr[4] = {bf2f(kxu.x), bf2f(kxu.y), bf2f(kxu.z), bf2f(kxu.w)};
        float kar[4] = {bf2f(kau.x), bf2f(kau.y), bf2f(kau.z), bf2f(kau.w)};
        float sx = kxr[0]*kxr[0] + kxr[1]*kxr[1] + kxr[2]*kxr[2] + kxr[3]*kxr[3];
        float sa = kar[0]*kar[0] + kar[1]*kar[1] + kar[2]*kar[2] + kar[3]*kar[3];
        #pragma unroll
        for (int off = 1; off < 16; off <<= 1) {
            sx += __shfl_xor(sx, off, 16);
            sa += __shfl_xor(sa, off, 16);
        }
        float ikx = 1.0f / fmaxf(sqrtf(sx), 1e-12f);
        float ika = 1.0f / fmaxf(sqrtf(sa), 1e-12f);
        unsigned short klo[4], khi[4];
        #pragma unroll
        for (int j = 0; j < 4; j++) {
            int jd = tid * 4 + j;
            float kx = kxr[j] * ikx * kx_scale[jd];
            float ka = kar[j] * ika * ka_scale[jd];
            float2 cssn = tb[jd];
            klo[j] = f2bf(kx * cssn.x - ka * cssn.y);
            khi[j] = f2bf(ka * cssn.x + kx * cssn.y);
        }
        unsigned short* kp = kbuf + ((size_t)b * SEQ + pos) * ROT;
        *(ushort4*)(kp + tid * 4)      = make_ushort4(klo[0], klo[1], klo[2], klo[3]);
        *(ushort4*)(kp + DH + tid * 4) = make_ushort4(khi[0], khi[1], khi[2], khi[3]);
    }
    // ---- V (transposed store, exact bf16 copy) ----
    if (tid >= 64 && tid < 96) {
        int iv = tid - 64;
        unsigned short* vT = vbufT + (size_t)b * ROT * SEQ + pos;
        const unsigned short* src; int d;
        if (iv < 16) { src = Px + DIM + DH + iv * 4;        d = iv * 4;              }
        else         { src = Pa + DIM + DH + (iv - 16) * 4; d = DH + (iv - 16) * 4;  }
        ushort4 v4 = *(const ushort4*)src;
        vT[(size_t)(d + 0) * SEQ] = v4.x;
        vT[(size_t)(d + 1) * SEQ] = v4.y;
        vT[(size_t)(d + 2) * SEQ] = v4.z;
        vT[(size_t)(d + 3) * SEQ] = v4.w;
    }
}

// ---------------------------------------------------------------------------
// MFMA flash attention (bf16, 32x32x16), R2 shape + double-buffered pipeline:
//   block = 4 waves x 32 q-rows = 128 q/block, grid (16,16,2) — the high-reuse
//   regime (FETCH ~16 MB).  K and V both staged via global_load_lds with the
//   XOR swizzle applied to the per-lane SOURCE address (dest must be
//   wave-uniform + lane*16).  Tile t+1 prefetched into the alternate buffer;
//   raw s_waitcnt vmcnt(8) + raw s_barrier keep the prefetch in flight across
//   the barrier (what __syncthreads' vmcnt(0) drain forbids).
// ---------------------------------------------------------------------------
__global__ __launch_bounds__(256, 2) void attn_kernel(
    const unsigned short* __restrict__ qbuf,
    const unsigned short* __restrict__ kbuf,
    const unsigned short* __restrict__ vbufT,
    float* __restrict__ out)
{
    const int qb = blockIdx.x, h = blockIdx.y, b = blockIdx.z;
    __shared__ __align__(16) unsigned short Ks[2][64 * 128];   // 2x16 KB
    __shared__ __align__(16) unsigned short Vs[2][128 * 64];   // 2x16 KB
    const int tid  = threadIdx.x;
    const int wave = tid >> 6, lane = tid & 63;
    const int m = lane & 31, hl = lane >> 5;
    const int q0 = qb * 128 + wave * 32;

    // Q resident (B-frag): chunk c covers d = c*16 + hl*8 + j
    bf16x8 qf[8];
    {
        const unsigned short* qp = qbuf + (((size_t)(b * HEADS + h)) * SEQ + q0 + m) * ROT + hl * 8;
        #pragma unroll
        for (int c = 0; c < 8; c++) qf[c] = *(const bf16x8*)(qp + c * 16);
    }

    f32x16 oacc[4];
    #pragma unroll
    for (int dt = 0; dt < 4; dt++) oacc[dt] = 0.0f;
    float lsum = 0.f;

    const unsigned short* kb_ = kbuf  + (size_t)b * SEQ * ROT;
    const unsigned short* vb_ = vbufT + (size_t)b * ROT * SEQ;

    // per-thread staging addresses (swizzle folded into the global source)
    const unsigned short* ksrc[4];
    const unsigned short* vsrc[4];
    unsigned ldsoff[4];
    #pragma unroll
    for (int i = 0; i < 4; i++) {
        int fg = i * 256 + tid;
        int krow = fg >> 4, kg = fg & 15;                 // K: 64 rows x 16 granules
        ksrc[i] = kb_ + (size_t)krow * ROT + ((kg ^ (krow & 15)) << 3);
        int rv = fg >> 3, gv = fg & 7;                    // V^T: 128 rows x 8 granules
        vsrc[i] = vb_ + (size_t)rv * SEQ + ((gv ^ (rv & 7)) << 3);
        ldsoff[i] = (unsigned)(i * 256 + wave * 64) * 16; // bytes, wave-uniform base
    }

    // stage tile 0 into buffer 0
    #pragma unroll
    for (int i = 0; i < 4; i++) {
        GL2LDS(ksrc[i], (char*)Ks[0] + ldsoff[i]);
        GL2LDS(vsrc[i], (char*)Vs[0] + ldsoff[i]);
    }

    for (int t = 0; t < 32; t++) {
        const int buf = t & 1;
        if (t < 31) {                         // prefetch t+1 into alternate buffer
            #pragma unroll
            for (int i = 0; i < 4; i++) {
                GL2LDS(ksrc[i] + (size_t)(t + 1) * 64 * ROT, (char*)Ks[buf ^ 1] + ldsoff[i]);
                GL2LDS(vsrc[i] + (t + 1) * 64,               (char*)Vs[buf ^ 1] + ldsoff[i]);
            }
        }
        CFENCE();
        if (t < 31) WAIT_VM8(); else WAIT_VM0();   // tile t's 8 loads are the oldest
        __builtin_amdgcn_s_barrier();
        CFENCE();

        #pragma unroll
        for (int kg = 0; kg < 2; kg++) {
            // S^T tile: 32 keys x 32 qrows
            f32x16 st = 0.0f;
            #pragma unroll
            for (int c = 0; c < 8; c++) {
                bf16x8 af = *(const bf16x8*)&Ks[buf][(kg * 32 + m) * 128 +
                                                     (((2 * c + hl) ^ (m & 15)) << 3)];
                st = __builtin_amdgcn_mfma_f32_32x32x16_bf16(af, qf[c], st, 0, 0, 0);
            }
            float p[16];
            #pragma unroll
            for (int r = 0; r < 16; r++) { p[r] = __expf(st[r]); lsum += p[r]; }

            // PV over two 16-key windows
            #pragma unroll
            for (int w = 0; w < 2; w++) {
                float pj[8];
                #pragma unroll
                for (int tq = 0; tq < 4; tq++) {
                    float send = hl ? p[8 * w + tq]     : p[8 * w + 4 + tq];
                    float own  = hl ? p[8 * w + 4 + tq] : p[8 * w + tq];
                    float recv = __shfl_xor(send, 32);
                    pj[tq]     = hl ? recv : own;
                    pj[4 + tq] = hl ? own  : recv;
                }
                bf16x8 aP;
                #pragma unroll
                for (int j = 0; j < 8; j++) aP[j] = (short)f2bf(pj[j]);
                #pragma unroll
                for (int dt = 0; dt < 4; dt++) {
                    int d = dt * 32 + m;
                    bf16x8 vf = *(const bf16x8*)&Vs[buf][d * 64 +
                                                         (((kg * 4 + w * 2 + hl) ^ (d & 7)) << 3)];
                    oacc[dt] = __builtin_amdgcn_mfma_f32_32x32x16_bf16(aP, vf, oacc[dt], 0, 0, 0);
                }
            }
        }

        CFENCE();
        __builtin_amdgcn_s_barrier();    // protect buf from t+2's prefetch overwrite
        CFENCE();
    }

    lsum += __shfl_xor(lsum, 32);    // add other half-lane's keys
    float* ob = out + ((size_t)(b * SEQ + q0)) * (HEADS * ROT) + h * ROT + m;
    #pragma unroll
    for (int r = 0; r < 16; r++) {
        int qrow = (r & 3) + 8 * (r >> 2) + 4 * hl;
        float linv = 1.0f / __shfl(lsum, qrow);
        float* orow = ob + (size_t)qrow * (HEADS * ROT);
        #pragma unroll
        for (int dt = 0; dt < 4; dt++) orow[dt * 32] = oacc[dt][r] * linv;
    }
}

// ---------------------------------------------------------------------------
extern "C" void kernel_launch(void* const* d_in, const int* in_sizes, int n_in,
                              void* d_out, int out_size, void* d_ws, size_t ws_size,
                              hipStream_t stream) {
    (void)in_sizes; (void)n_in; (void)out_size; (void)ws_size;
    const float* x        = (const float*)d_in[0];
    const float* a        = (const float*)d_in[1];
    const float* Wq_x     = (const float*)d_in[2];
    const float* Wkv_x    = (const float*)d_in[3];
    const float* Wq_a     = (const float*)d_in[4];
    const float* Wkv_a    = (const float*)d_in[5];
    const float* qx_scale = (const float*)d_in[6];
    const float* qa_scale = (const float*)d_in[7];
    const float* kx_scale = (const float*)d_in[8];
    const float* ka_scale = (const float*)d_in[9];
    float* out = (float*)d_out;

    unsigned short* Pbf   = (unsigned short*)d_ws;
    unsigned short* qbuf  = Pbf   + (size_t)2 * ROWS * PCOLS;
    unsigned short* kbuf  = qbuf  + (size_t)BATCH * HEADS * SEQ * ROT;
    unsigned short* vbufT = kbuf  + (size_t)BATCH * SEQ * ROT;
    unsigned short* xbf   = vbufT + (size_t)BATCH * SEQ * ROT;
    unsigned short* wbf   = xbf   + (size_t)2 * ROWS * DIM;
    float2*         tbl   = (float2*)(wbf + (size_t)2 * PCOLS * DIM);

    convert_kernel<<<dim3(2752), 256, 0, stream>>>(x, a, Wq_x, Wkv_x, Wq_a, Wkv_a,
                                                   xbf, wbf, tbl);
    mfma_gemm_kernel<<<dim3(32, 9, 2), 256, 0, stream>>>(xbf, wbf, Pbf);
    fuse_kernel<<<dim3(ROWS), 256, 0, stream>>>(Pbf, qx_scale, qa_scale, kx_scale, ka_scale,
                                                tbl, qbuf, kbuf, vbufT);
    attn_kernel<<<dim3(SEQ / 128, HEADS, BATCH), 256, 0, stream>>>(qbuf, kbuf, vbufT, out);
}